// Round 1
// baseline (954.414 us; speedup 1.0000x reference)
//
#include <hip/hip_runtime.h>

#define E_DIM 512
#define N_E   1024
#define HW_   4096
#define NVEC  65536                 // 16 * 64 * 64
#define BSTRIDE (E_DIM * HW_)       // per-batch stride in z: 2097152
#define ZQ_ELEMS 33554432           // 16*512*64*64
#define TM 128
#define TJ 128
#define KC 32

// ---------------- prep: codebook norms + zero loss accumulator ----------------
__global__ __launch_bounds__(64) void vq_prep(const float* __restrict__ cb,
                                              float* __restrict__ ynorm,
                                              float* __restrict__ loss_acc) {
    int j = blockIdx.x;           // 1024 blocks, 64 threads each
    int l = threadIdx.x;
    float s = 0.f;
    for (int c = l; c < E_DIM; c += 64) { float v = cb[j * E_DIM + c]; s += v * v; }
#pragma unroll
    for (int off = 32; off > 0; off >>= 1) s += __shfl_xor(s, off);
    if (l == 0) ynorm[j] = s;
    if (j == 0 && l == 0) *loss_acc = 0.f;
}

// ---------------- main: distances + argmin + loss partials ----------------
// block = 256 threads, owns TM=128 vectors x all 1024 codes.
// thread (tx = t&15, ty = t>>4) computes an 8x8 micro-tile of dot products.
__global__ __launch_bounds__(256) void vq_dist(const float* __restrict__ z,
                                               const float* __restrict__ cb,
                                               const float* __restrict__ ynorm,
                                               int* __restrict__ ws_idx,
                                               float* __restrict__ loss_acc,
                                               float* __restrict__ out_idx) {
    __shared__ float As[KC][TM];     // 16 KB: A chunk, [k][m]
    __shared__ float Bs[KC][TJ];     // 16 KB: B chunk, [k][j]
    __shared__ float zn[TM];         // ||z||^2 per row
    __shared__ float pr[256];

    const int t   = threadIdx.x;
    const int m0  = blockIdx.x * TM;       // global vector base (never crosses batch)
    const int b   = m0 >> 12;
    const int hw0 = m0 & 4095;
    const float* zb = z + (long)b * BSTRIDE + hw0;   // zb[c*HW_ + m_local]

    // --- znorm for this block's 128 rows ---
    {
        int ml = t & 127, kh = t >> 7;
        float s = 0.f;
        for (int c = kh; c < E_DIM; c += 2) { float v = zb[(long)c * HW_ + ml]; s += v * v; }
        pr[t] = s;
        __syncthreads();
        if (t < TM) zn[t] = pr[t] + pr[t + 128];
        __syncthreads();
    }

    const int tx = t & 15, ty = t >> 4;
    float bestd[8];
    int   bestj[8];
#pragma unroll
    for (int i = 0; i < 8; ++i) { bestd[i] = 3.4e38f; bestj[i] = 0; }

    for (int tj = 0; tj < N_E / TJ; ++tj) {
        float acc[8][8];
#pragma unroll
        for (int i = 0; i < 8; ++i)
#pragma unroll
            for (int q = 0; q < 8; ++q) acc[i][q] = 0.f;

        for (int kc = 0; kc < E_DIM; kc += KC) {
            __syncthreads();   // protect previous chunk's reads
            // stage A: 128 m x 32 c, float4 along m (coalesced)
#pragma unroll
            for (int r = 0; r < 4; ++r) {
                int cc = (t >> 5) + r * 8;
                int mq = (t & 31) * 4;
                float4 v = *(const float4*)&zb[(long)(kc + cc) * HW_ + mq];
                *(float4*)&As[cc][mq] = v;
            }
            // stage B: 128 j x 32 c, float4 along c (coalesced), transpose into LDS
            const float* cbt = cb + (long)(tj * TJ) * E_DIM + kc;
#pragma unroll
            for (int r = 0; r < 4; ++r) {
                int jj = (t >> 3) + r * 32;
                int cq = (t & 7) * 4;
                float4 v = *(const float4*)&cbt[(long)jj * E_DIM + cq];
                Bs[cq + 0][jj] = v.x; Bs[cq + 1][jj] = v.y;
                Bs[cq + 2][jj] = v.z; Bs[cq + 3][jj] = v.w;
            }
            __syncthreads();
            // compute: 32 k-steps, 64 FMA each
#pragma unroll
            for (int kk = 0; kk < KC; ++kk) {
                float a[8], bb[8];
                *(float4*)&a[0]  = *(const float4*)&As[kk][ty * 8];
                *(float4*)&a[4]  = *(const float4*)&As[kk][ty * 8 + 4];
                *(float4*)&bb[0] = *(const float4*)&Bs[kk][tx * 8];
                *(float4*)&bb[4] = *(const float4*)&Bs[kk][tx * 8 + 4];
#pragma unroll
                for (int i = 0; i < 8; ++i)
#pragma unroll
                    for (int q = 0; q < 8; ++q)
                        acc[i][q] = fmaf(a[i], bb[q], acc[i][q]);
            }
        }

        // epilogue for this j-tile: d = znorm + ynorm - 2*dot (same form as np ref)
        int jg0 = tj * TJ + tx * 8;
#pragma unroll
        for (int q = 0; q < 8; ++q) {
            float yn = ynorm[jg0 + q];
            int jg = jg0 + q;
#pragma unroll
            for (int i = 0; i < 8; ++i) {
                float d = (zn[ty * 8 + i] + yn) - 2.0f * acc[i][q];
                if (d < bestd[i] || (d == bestd[i] && jg < bestj[i])) {
                    bestd[i] = d; bestj[i] = jg;
                }
            }
        }
    }

    // reduce across the 16 tx lanes (low 4 bits of lane id) — lexicographic (d, j)
#pragma unroll
    for (int off = 1; off < 16; off <<= 1) {
#pragma unroll
        for (int i = 0; i < 8; ++i) {
            float od = __shfl_xor(bestd[i], off);
            int   oj = __shfl_xor(bestj[i], off);
            if (od < bestd[i] || (od == bestd[i] && oj < bestj[i])) {
                bestd[i] = od; bestj[i] = oj;
            }
        }
    }
    if (tx == 0) {
        float s = 0.f;
#pragma unroll
        for (int i = 0; i < 8; ++i) {
            int mg = m0 + ty * 8 + i;
            ws_idx[mg]  = bestj[i];
            out_idx[mg] = (float)bestj[i];   // indices compared as floats
            s += bestd[i];
        }
        atomicAdd(loss_acc, s);
    }
}

// ---------------- gather z_q (B,C,H,W) + finalize loss ----------------
__global__ __launch_bounds__(256) void vq_gather(const float* __restrict__ cb,
                                                 const int* __restrict__ ws_idx,
                                                 const float* __restrict__ loss_acc,
                                                 float* __restrict__ out) {
    int tid = blockIdx.x * 256 + threadIdx.x;   // 8,388,608 threads
    int hw  = tid & 4095;
    int c4  = (tid >> 12) & 127;
    int b   = tid >> 19;
    int n   = (b << 12) | hw;
    int j   = ws_idx[n];
    float4 v = ((const float4*)cb)[j * 128 + c4];
    float* o = out + (long)b * BSTRIDE + (long)(c4 * 4) * HW_ + hw;
    o[0]        = v.x;
    o[HW_]      = v.y;
    o[2 * HW_]  = v.z;
    o[3 * HW_]  = v.w;
    if (tid == 0) out[ZQ_ELEMS] = 1.25f * (*loss_acc) / (float)ZQ_ELEMS;
}

extern "C" void kernel_launch(void* const* d_in, const int* in_sizes, int n_in,
                              void* d_out, int out_size, void* d_ws, size_t ws_size,
                              hipStream_t stream) {
    const float* z  = (const float*)d_in[0];   // (16,512,64,64)
    const float* cb = (const float*)d_in[1];   // (1024,512)
    float* out = (float*)d_out;                // [z_q 33554432][loss 1][indices 65536]

    float* wsf      = (float*)d_ws;
    float* loss_acc = wsf;                     // 1 float
    float* ynorm    = wsf + 16;                // 1024 floats
    int*   ws_idx   = (int*)((char*)d_ws + 8192);  // 65536 ints

    vq_prep<<<N_E, 64, 0, stream>>>(cb, ynorm, loss_acc);
    vq_dist<<<NVEC / TM, 256, 0, stream>>>(z, cb, ynorm, ws_idx, loss_acc,
                                           out + ZQ_ELEMS + 1);
    vq_gather<<<(16 * 128 * 4096) / 256, 256, 0, stream>>>(cb, ws_idx, loss_acc, out);
}

// Round 2
// 713.800 us; speedup vs baseline: 1.3371x; 1.3371x over previous
//
#include <hip/hip_runtime.h>

#define N_E   1024
#define E_DIM 512
#define HW_   4096
#define NVEC  65536                 // 16 * 64 * 64
#define ZQ_ELEMS 33554432           // 16*512*64*64
#define BETA 0.25f

typedef _Float16 half8 __attribute__((ext_vector_type(8), aligned(16)));
typedef float f32x4 __attribute__((ext_vector_type(4)));
typedef unsigned int u32x4 __attribute__((ext_vector_type(4), aligned(16)));

union H16 { _Float16 f; unsigned short u; };
__device__ __forceinline__ unsigned short f2h(float v) { H16 h; h.f = (_Float16)v; return h.u; }

// ---------------- prep: codebook -> fp16 hi/lo (x32), ynorm (x1024), zero loss ----------------
__global__ __launch_bounds__(64) void vq_prep(const float* __restrict__ cb,
    unsigned short* __restrict__ Bh, unsigned short* __restrict__ Bl,
    float* __restrict__ ynorm, float* __restrict__ loss_acc) {
    int j = blockIdx.x, l = threadIdx.x;
    float s = 0.f;
    for (int i = 0; i < 8; ++i) {
        int c = l + (i << 6);
        float v = cb[(j << 9) + c];
        s += v * v;
        float vs = 32.f * v;
        _Float16 hi = (_Float16)vs;
        H16 hh; hh.f = hi;
        Bh[(j << 9) + c] = hh.u;
        Bl[(j << 9) + c] = f2h(vs - (float)hi);
    }
#pragma unroll
    for (int off = 32; off > 0; off >>= 1) s += __shfl_xor(s, off);
    if (l == 0) ynorm[j] = s * 1024.f;        // scaled by 32^2 to match scaled dot
    if (j == 0 && l == 0) *loss_acc = 0.f;
}

// ---------------- pack: z (B,C,H,W) fp32 -> A[m][k] fp16 hi/lo (x32), transposed ----------------
__global__ __launch_bounds__(256) void vq_pack(const float* __restrict__ z,
    unsigned short* __restrict__ Ah, unsigned short* __restrict__ Al, int base_b) {
    __shared__ float T[64][65];
    int bid = blockIdx.x;
    int hw0 = (bid & 63) << 6;
    int c0 = ((bid >> 6) & 7) << 6;
    int bb = (bid >> 9) + base_b;
    int t = threadIdx.x;
    int hl = t & 63, cl = t >> 6;
    const float* zp = z + ((long)((bb << 9) + c0 + cl)) * 4096 + hw0 + hl;
#pragma unroll
    for (int i = 0; i < 16; ++i)
        T[cl + 4 * i][hl] = zp[(long)(4 * i) * 4096];
    __syncthreads();
    int hr = t >> 2, cg = (t & 3) << 4;
    long m = ((long)(bb - base_b) << 12) + hw0 + hr;   // phase-local row
    unsigned short h8[16], l8[16];
#pragma unroll
    for (int e = 0; e < 16; ++e) {
        float v = 32.f * T[cg + e][hr];
        _Float16 hi = (_Float16)v;
        H16 hh; hh.f = hi;
        h8[e] = hh.u;
        l8[e] = f2h(v - (float)hi);
    }
    long o = m * 512 + c0 + cg;
    *(u32x4*)&Ah[o]     = *(u32x4*)&h8[0];
    *(u32x4*)&Ah[o + 8] = *(u32x4*)&h8[8];
    *(u32x4*)&Al[o]     = *(u32x4*)&l8[0];
    *(u32x4*)&Al[o + 8] = *(u32x4*)&l8[8];
}

// ---------------- dist: MFMA fp16-split GEMM + fused argmin ----------------
// 512 threads (8 waves: 2m x 4j), block tile 128m x 512j, K chunks of 32 (hi+lo co-staged).
// acc = hi*hi + lo*hi + hi*lo  (3 MFMA per fragment pair). argmin over j of (ynorm - 2*dot).
__global__ __launch_bounds__(512, 2) void vq_dist(
    const unsigned short* __restrict__ Ah, const unsigned short* __restrict__ Al,
    const unsigned short* __restrict__ Bh, const unsigned short* __restrict__ Bl,
    const float* __restrict__ ynorm, int* __restrict__ ws_idx,
    float* __restrict__ out_idx, int mbase) {

    __shared__ _Float16 sA[128][64];        // [m][hi:0..31 | lo:32..63], slot-swizzled
    __shared__ _Float16 sB[2][512][64];     // double-buffered
    __shared__ float bwd[8][4][4][4];       // per-wave running best dist [wid][kg][mt][r]
    __shared__ int   bwj[8][4][4][4];

    const int t = threadIdx.x;
    const int l = t & 63, wid = t >> 6;
    const int lid = l & 15, kg = l >> 4;
    const int wm64 = (wid >> 2) << 6;       // 0 or 64
    const int wj128 = (wid & 3) << 7;       // 0..384
    const int m0 = blockIdx.x << 7;         // phase-local m base

    // staging role: threads 0..255 stage "hi", 256..511 stage "lo"
    const int kind = t >> 8;
    const int tt = t & 255;
    const int srow = tt >> 1;               // 0..127
    const int sch = (tt & 1) << 4;          // 0 or 16 halves
    const int slotbase = (kind << 2) + ((tt & 1) << 1);   // pre-swizzle slot

    const unsigned short* Agp = (kind ? Al : Ah) + (((long)(m0 + srow)) << 9) + sch;
    const unsigned short* Bgp = (kind ? Bl : Bh) + (((long)srow) << 9) + sch;

    if (t < 512) { ((float*)bwd)[t] = 3.4e38f; ((int*)bwj)[t] = 0x7fffffff; }

    u32x4 aA0a, aA0b, aA1a, aA1b;           // A staging double set (scalarized)
    u32x4 br0, br1, br2, br3, br4, br5, br6, br7;

    auto LOADB = [&](int c) {
        int kc = (c & 15) << 5;
        const unsigned short* p = Bgp + (((long)(c >> 4)) << 18) + kc;  // tj*512 rows *512
        br0 = *(const u32x4*)(p);              br1 = *(const u32x4*)(p + 8);
        br2 = *(const u32x4*)(p + 65536);      br3 = *(const u32x4*)(p + 65536 + 8);
        br4 = *(const u32x4*)(p + 131072);     br5 = *(const u32x4*)(p + 131072 + 8);
        br6 = *(const u32x4*)(p + 196608);     br7 = *(const u32x4*)(p + 196608 + 8);
    };
    auto STOREB = [&](int buf) {
        int x0 = (slotbase + 0) ^ (srow & 7), x1 = (slotbase + 1) ^ (srow & 7);
        *(u32x4*)&sB[buf][srow][x0 << 3] = br0;       *(u32x4*)&sB[buf][srow][x1 << 3] = br1;
        int r1 = srow + 128, y0 = (slotbase + 0) ^ (r1 & 7), y1 = (slotbase + 1) ^ (r1 & 7);
        *(u32x4*)&sB[buf][r1][y0 << 3] = br2;         *(u32x4*)&sB[buf][r1][y1 << 3] = br3;
        int r2 = srow + 256, z0 = (slotbase + 0) ^ (r2 & 7), z1 = (slotbase + 1) ^ (r2 & 7);
        *(u32x4*)&sB[buf][r2][z0 << 3] = br4;         *(u32x4*)&sB[buf][r2][z1 << 3] = br5;
        int r3 = srow + 384, w0 = (slotbase + 0) ^ (r3 & 7), w1 = (slotbase + 1) ^ (r3 & 7);
        *(u32x4*)&sB[buf][r3][w0 << 3] = br6;         *(u32x4*)&sB[buf][r3][w1 << 3] = br7;
    };
    auto LDA = [&](int c, u32x4& ra, u32x4& rb) {
        int kc = (c & 15) << 5;
        ra = *(const u32x4*)(Agp + kc);
        rb = *(const u32x4*)(Agp + kc + 8);
    };
    auto STA = [&](const u32x4& ra, const u32x4& rb) {
        int x0 = (slotbase + 0) ^ (srow & 7), x1 = (slotbase + 1) ^ (srow & 7);
        *(u32x4*)&sA[srow][x0 << 3] = ra;
        *(u32x4*)&sA[srow][x1 << 3] = rb;
    };

    f32x4 acc[4][8];
    auto ZERO = [&]() {
#pragma unroll
        for (int mt = 0; mt < 4; ++mt)
#pragma unroll
            for (int jt = 0; jt < 8; ++jt) acc[mt][jt] = {0.f, 0.f, 0.f, 0.f};
    };

    auto COMPUTE = [&](int buf) {
        half8 ah[4], alo[4];
#pragma unroll
        for (int mt = 0; mt < 4; ++mt) {
            int row = wm64 + (mt << 4) + lid;
            ah[mt]  = *(const half8*)&sA[row][((0 + kg) ^ (row & 7)) << 3];
            alo[mt] = *(const half8*)&sA[row][((4 + kg) ^ (row & 7)) << 3];
        }
#pragma unroll
        for (int jt = 0; jt < 8; ++jt) {
            int row = wj128 + (jt << 4) + lid;
            half8 bh = *(const half8*)&sB[buf][row][((0 + kg) ^ (row & 7)) << 3];
            half8 bl = *(const half8*)&sB[buf][row][((4 + kg) ^ (row & 7)) << 3];
#pragma unroll
            for (int mt = 0; mt < 4; ++mt) {
                acc[mt][jt] = __builtin_amdgcn_mfma_f32_16x16x32_f16(ah[mt],  bh, acc[mt][jt], 0, 0, 0);
                acc[mt][jt] = __builtin_amdgcn_mfma_f32_16x16x32_f16(alo[mt], bh, acc[mt][jt], 0, 0, 0);
                acc[mt][jt] = __builtin_amdgcn_mfma_f32_16x16x32_f16(ah[mt],  bl, acc[mt][jt], 0, 0, 0);
            }
        }
    };

    auto EPILOGUE = [&](int tj) {
        float yn[8];
#pragma unroll
        for (int jt = 0; jt < 8; ++jt)
            yn[jt] = ynorm[(tj << 9) + wj128 + (jt << 4) + lid];
#pragma unroll
        for (int mt = 0; mt < 4; ++mt)
#pragma unroll
            for (int r = 0; r < 4; ++r) {
                float bd = 3.4e38f; int bj = 0x7fffffff;
#pragma unroll
                for (int jt = 0; jt < 8; ++jt) {
                    int jg = (tj << 9) + wj128 + (jt << 4) + lid;
                    float d = yn[jt] - 2.f * acc[mt][jt][r];
                    if (d < bd || (d == bd && jg < bj)) { bd = d; bj = jg; }
                }
#pragma unroll
                for (int off = 1; off < 16; off <<= 1) {
                    float od = __shfl_xor(bd, off);
                    int   oj = __shfl_xor(bj, off);
                    if (od < bd || (od == bd && oj < bj)) { bd = od; bj = oj; }
                }
                if (lid == 0) {
                    float D = bwd[wid][kg][mt][r]; int J = bwj[wid][kg][mt][r];
                    if (bd < D || (bd == D && bj < J)) {
                        bwd[wid][kg][mt][r] = bd; bwj[wid][kg][mt][r] = bj;
                    }
                }
            }
    };

    // prologue: stage chunk 0, prefetch chunk 1
    LDA(0, aA0a, aA0b); LOADB(0);
    STA(aA0a, aA0b); STOREB(0);
    LDA(1, aA1a, aA1b); LOADB(1);
    __syncthreads();
    ZERO();

    for (int cp = 0; cp < 16; ++cp) {
        const int c0v = cp << 1, c1v = c0v + 1;
        // ---- even chunk (buf 0) ----
        STOREB(1);                                        // B(c0v+1)
        if (c0v < 30) { LDA(c0v + 2, aA0a, aA0b); LOADB(c0v + 2); }
        COMPUTE(0);
        __syncthreads();                                  // readers of sA/sB[0] done
        STA(aA1a, aA1b);                                  // A(c0v+1)
        __syncthreads();
        // ---- odd chunk (buf 1) ----
        if (c1v < 31) STOREB(0);                          // B(c1v+1)
        if (c1v < 30) { LDA(c1v + 2, aA1a, aA1b); LOADB(c1v + 2); }
        COMPUTE(1);
        if ((c1v & 15) == 15) { EPILOGUE(c1v >> 4); ZERO(); }
        __syncthreads();
        if (c1v < 31) { STA(aA0a, aA0b); __syncthreads(); }
    }

    // final merge across the 4 j-waves + writeout
    if (t < 128) {
        int wmv = t >> 6, local = t & 63;
        int mt = local >> 4, kg2 = (local >> 2) & 3, r = local & 3;
        float bd = bwd[(wmv << 2)][kg2][mt][r];
        int   bj = bwj[(wmv << 2)][kg2][mt][r];
#pragma unroll
        for (int wjv = 1; wjv < 4; ++wjv) {
            float od = bwd[(wmv << 2) + wjv][kg2][mt][r];
            int   oj = bwj[(wmv << 2) + wjv][kg2][mt][r];
            if (od < bd || (od == bd && oj < bj)) { bd = od; bj = oj; }
        }
        int m = mbase + m0 + (wmv << 6) + (mt << 4) + (kg2 << 2) + r;
        ws_idx[m] = bj;
        out_idx[m] = (float)bj;
    }
}

// ---------------- gather z_q (B,C,H,W) + direct loss partials ----------------
__global__ __launch_bounds__(256) void vq_gather(const float* __restrict__ cb,
    const float* __restrict__ z, const int* __restrict__ ws_idx,
    float* __restrict__ out, float* __restrict__ loss_acc) {
    int tid = blockIdx.x * 256 + threadIdx.x;
    int hw = tid & 4095;
    int c4 = (tid >> 12) & 127;
    int b = tid >> 19;
    int n = (b << 12) | hw;
    int j = ws_idx[n];
    float4 v = ((const float4*)cb)[(j << 7) + c4];
    long zo = ((long)((b << 9) + (c4 << 2))) * 4096 + hw;
    float z0 = z[zo], z1 = z[zo + 4096], z2 = z[zo + 8192], z3 = z[zo + 12288];
    out[zo] = v.x; out[zo + 4096] = v.y; out[zo + 8192] = v.z; out[zo + 12288] = v.w;
    float d0 = v.x - z0, d1 = v.y - z1, d2 = v.z - z2, d3 = v.w - z3;
    float s = d0 * d0 + d1 * d1 + d2 * d2 + d3 * d3;
#pragma unroll
    for (int off = 32; off > 0; off >>= 1) s += __shfl_xor(s, off);
    __shared__ float ps[4];
    if ((threadIdx.x & 63) == 0) ps[threadIdx.x >> 6] = s;
    __syncthreads();
    if (threadIdx.x == 0) atomicAdd(loss_acc, ps[0] + ps[1] + ps[2] + ps[3]);
}

__global__ void vq_final(const float* __restrict__ loss_acc, float* __restrict__ out) {
    out[ZQ_ELEMS] = (1.f + BETA) * (*loss_acc) / 33554432.f;
}

extern "C" void kernel_launch(void* const* d_in, const int* in_sizes, int n_in,
                              void* d_out, int out_size, void* d_ws, size_t ws_size,
                              hipStream_t stream) {
    const float* z  = (const float*)d_in[0];   // (16,512,64,64) fp32
    const float* cb = (const float*)d_in[1];   // (1024,512) fp32
    float* out = (float*)d_out;                // [z_q | loss | indices(float)]
    char* ws = (char*)d_ws;

    float* loss_acc = (float*)ws;
    float* ynorm    = (float*)(ws + 1024);
    int*   ws_idx   = (int*)(ws + 8192);
    unsigned short* Bh = (unsigned short*)(ws + (1L << 20));
    unsigned short* Bl = (unsigned short*)(ws + (2L << 20));
    const size_t base = 3L << 20;
    unsigned short* Ah = (unsigned short*)(ws + base);

    // pick M-phasing from available workspace (deterministic in ws_size)
    int nphase = 1;
    while (nphase < 16) {
        size_t Asz = (size_t)(65536 / nphase) * 512 * 2;
        if (base + 2 * Asz <= ws_size) break;
        nphase <<= 1;
    }
    size_t Asz = (size_t)(65536 / nphase) * 512 * 2;
    unsigned short* Al = (unsigned short*)(ws + base + Asz);

    vq_prep<<<N_E, 64, 0, stream>>>(cb, Bh, Bl, ynorm, loss_acc);
    int PM = 65536 / nphase;
    for (int p = 0; p < nphase; ++p) {
        vq_pack<<<8192 / nphase, 256, 0, stream>>>(z, Ah, Al, p * (16 / nphase));
        vq_dist<<<PM / 128, 512, 0, stream>>>(Ah, Al, Bh, Bl, ynorm, ws_idx,
                                              out + ZQ_ELEMS + 1, p * PM);
    }
    vq_gather<<<(NVEC / 256) * 128, 256, 0, stream>>>(cb, z, ws_idx, out, loss_acc);
    vq_final<<<1, 1, 0, stream>>>(loss_acc, out);
}

// Round 3
// 366.684 us; speedup vs baseline: 2.6028x; 1.9466x over previous
//
#include <hip/hip_runtime.h>

#define N_E   1024
#define E_DIM 512
#define HW_   4096
#define NVEC  65536                 // 16 * 64 * 64
#define ZQ_ELEMS 33554432           // 16*512*64*64
#define BETA 0.25f
#define NPART 8192                  // gather partial-sum count

typedef _Float16 half8 __attribute__((ext_vector_type(8), aligned(16)));
typedef float f32x4 __attribute__((ext_vector_type(4)));
typedef unsigned int u32x4 __attribute__((ext_vector_type(4), aligned(16)));

union H16 { _Float16 f; unsigned short u; };
__device__ __forceinline__ unsigned short f2h(float v) { H16 h; h.f = (_Float16)v; return h.u; }

// ---------------- prep: codebook -> fp16 hi/lo (x32), ynorm (x1024) ----------------
__global__ __launch_bounds__(64) void vq_prep(const float* __restrict__ cb,
    unsigned short* __restrict__ Bh, unsigned short* __restrict__ Bl,
    float* __restrict__ ynorm) {
    int j = blockIdx.x, l = threadIdx.x;
    float s = 0.f;
    for (int i = 0; i < 8; ++i) {
        int c = l + (i << 6);
        float v = cb[(j << 9) + c];
        s += v * v;
        float vs = 32.f * v;
        _Float16 hi = (_Float16)vs;
        H16 hh; hh.f = hi;
        Bh[(j << 9) + c] = hh.u;
        Bl[(j << 9) + c] = f2h(vs - (float)hi);
    }
#pragma unroll
    for (int off = 32; off > 0; off >>= 1) s += __shfl_xor(s, off);
    if (l == 0) ynorm[j] = s * 1024.f;        // scaled by 32^2 to match scaled dot
}

// ---------------- pack: z (B,C,H,W) fp32 -> A[m][k] fp16 hi/lo (x32), transposed ----------------
__global__ __launch_bounds__(256) void vq_pack(const float* __restrict__ z,
    unsigned short* __restrict__ Ah, unsigned short* __restrict__ Al, int base_b) {
    __shared__ float T[64][65];
    int bid = blockIdx.x;
    int hw0 = (bid & 63) << 6;
    int c0 = ((bid >> 6) & 7) << 6;
    int bb = (bid >> 9) + base_b;
    int t = threadIdx.x;
    int hl = t & 63, cl = t >> 6;
    const float* zp = z + ((long)((bb << 9) + c0 + cl)) * 4096 + hw0 + hl;
#pragma unroll
    for (int i = 0; i < 16; ++i)
        T[cl + 4 * i][hl] = zp[(long)(4 * i) * 4096];
    __syncthreads();
    int hr = t >> 2, cg = (t & 3) << 4;
    long m = ((long)(bb - base_b) << 12) + hw0 + hr;   // phase-local row
    unsigned short h8[16], l8[16];
#pragma unroll
    for (int e = 0; e < 16; ++e) {
        float v = 32.f * T[cg + e][hr];
        _Float16 hi = (_Float16)v;
        H16 hh; hh.f = hi;
        h8[e] = hh.u;
        l8[e] = f2h(v - (float)hi);
    }
    long o = m * 512 + c0 + cg;
    *(u32x4*)&Ah[o]     = *(u32x4*)&h8[0];
    *(u32x4*)&Ah[o + 8] = *(u32x4*)&h8[8];
    *(u32x4*)&Al[o]     = *(u32x4*)&l8[0];
    *(u32x4*)&Al[o + 8] = *(u32x4*)&l8[8];
}

// ---------------- dist: MFMA fp16-split GEMM + fused argmin ----------------
// 512 threads (8 waves: 2m x 4j), block tile 128m x 512j, K chunks of 32 (hi+lo co-staged).
// acc = hi*hi + lo*hi + hi*lo  (3 MFMA per fragment pair). argmin over j of (ynorm - 2*dot).
__global__ __launch_bounds__(512, 2) void vq_dist(
    const unsigned short* __restrict__ Ah, const unsigned short* __restrict__ Al,
    const unsigned short* __restrict__ Bh, const unsigned short* __restrict__ Bl,
    const float* __restrict__ ynorm, int* __restrict__ ws_idx,
    float* __restrict__ out_idx, int mbase) {

    __shared__ _Float16 sA[128][64];        // [m][hi:0..31 | lo:32..63], slot-swizzled
    __shared__ _Float16 sB[2][512][64];     // double-buffered
    __shared__ float bwd[8][4][4][4];       // per-wave running best dist [wid][kg][mt][r]
    __shared__ int   bwj[8][4][4][4];

    const int t = threadIdx.x;
    const int l = t & 63, wid = t >> 6;
    const int lid = l & 15, kg = l >> 4;
    const int wm64 = (wid >> 2) << 6;       // 0 or 64
    const int wj128 = (wid & 3) << 7;       // 0..384
    const int m0 = blockIdx.x << 7;         // phase-local m base

    // staging role: threads 0..255 stage "hi", 256..511 stage "lo"
    const int kind = t >> 8;
    const int tt = t & 255;
    const int srow = tt >> 1;               // 0..127
    const int sch = (tt & 1) << 4;          // 0 or 16 halves
    const int slotbase = (kind << 2) + ((tt & 1) << 1);   // pre-swizzle slot

    const unsigned short* Agp = (kind ? Al : Ah) + (((long)(m0 + srow)) << 9) + sch;
    const unsigned short* Bgp = (kind ? Bl : Bh) + (((long)srow) << 9) + sch;

    if (t < 512) { ((float*)bwd)[t] = 3.4e38f; ((int*)bwj)[t] = 0x7fffffff; }

    u32x4 aA0a, aA0b, aA1a, aA1b;           // A staging double set (scalarized)
    u32x4 br0, br1, br2, br3, br4, br5, br6, br7;

    auto LOADB = [&](int c) {
        int kc = (c & 15) << 5;
        const unsigned short* p = Bgp + (((long)(c >> 4)) << 18) + kc;  // tj*512 rows *512
        br0 = *(const u32x4*)(p);              br1 = *(const u32x4*)(p + 8);
        br2 = *(const u32x4*)(p + 65536);      br3 = *(const u32x4*)(p + 65536 + 8);
        br4 = *(const u32x4*)(p + 131072);     br5 = *(const u32x4*)(p + 131072 + 8);
        br6 = *(const u32x4*)(p + 196608);     br7 = *(const u32x4*)(p + 196608 + 8);
    };
    auto STOREB = [&](int buf) {
        int x0 = (slotbase + 0) ^ (srow & 7), x1 = (slotbase + 1) ^ (srow & 7);
        *(u32x4*)&sB[buf][srow][x0 << 3] = br0;       *(u32x4*)&sB[buf][srow][x1 << 3] = br1;
        int r1 = srow + 128, y0 = (slotbase + 0) ^ (r1 & 7), y1 = (slotbase + 1) ^ (r1 & 7);
        *(u32x4*)&sB[buf][r1][y0 << 3] = br2;         *(u32x4*)&sB[buf][r1][y1 << 3] = br3;
        int r2 = srow + 256, z0 = (slotbase + 0) ^ (r2 & 7), z1 = (slotbase + 1) ^ (r2 & 7);
        *(u32x4*)&sB[buf][r2][z0 << 3] = br4;         *(u32x4*)&sB[buf][r2][z1 << 3] = br5;
        int r3 = srow + 384, w0 = (slotbase + 0) ^ (r3 & 7), w1 = (slotbase + 1) ^ (r3 & 7);
        *(u32x4*)&sB[buf][r3][w0 << 3] = br6;         *(u32x4*)&sB[buf][r3][w1 << 3] = br7;
    };
    auto LDA = [&](int c, u32x4& ra, u32x4& rb) {
        int kc = (c & 15) << 5;
        ra = *(const u32x4*)(Agp + kc);
        rb = *(const u32x4*)(Agp + kc + 8);
    };
    auto STA = [&](const u32x4& ra, const u32x4& rb) {
        int x0 = (slotbase + 0) ^ (srow & 7), x1 = (slotbase + 1) ^ (srow & 7);
        *(u32x4*)&sA[srow][x0 << 3] = ra;
        *(u32x4*)&sA[srow][x1 << 3] = rb;
    };

    f32x4 acc[4][8];
    auto ZERO = [&]() {
#pragma unroll
        for (int mt = 0; mt < 4; ++mt)
#pragma unroll
            for (int jt = 0; jt < 8; ++jt) acc[mt][jt] = {0.f, 0.f, 0.f, 0.f};
    };

    auto COMPUTE = [&](int buf) {
        half8 ah[4], alo[4];
#pragma unroll
        for (int mt = 0; mt < 4; ++mt) {
            int row = wm64 + (mt << 4) + lid;
            ah[mt]  = *(const half8*)&sA[row][((0 + kg) ^ (row & 7)) << 3];
            alo[mt] = *(const half8*)&sA[row][((4 + kg) ^ (row & 7)) << 3];
        }
#pragma unroll
        for (int jt = 0; jt < 8; ++jt) {
            int row = wj128 + (jt << 4) + lid;
            half8 bh = *(const half8*)&sB[buf][row][((0 + kg) ^ (row & 7)) << 3];
            half8 bl = *(const half8*)&sB[buf][row][((4 + kg) ^ (row & 7)) << 3];
#pragma unroll
            for (int mt = 0; mt < 4; ++mt) {
                acc[mt][jt] = __builtin_amdgcn_mfma_f32_16x16x32_f16(ah[mt],  bh, acc[mt][jt], 0, 0, 0);
                acc[mt][jt] = __builtin_amdgcn_mfma_f32_16x16x32_f16(alo[mt], bh, acc[mt][jt], 0, 0, 0);
                acc[mt][jt] = __builtin_amdgcn_mfma_f32_16x16x32_f16(ah[mt],  bl, acc[mt][jt], 0, 0, 0);
            }
        }
    };

    auto EPILOGUE = [&](int tj) {
        float yn[8];
#pragma unroll
        for (int jt = 0; jt < 8; ++jt)
            yn[jt] = ynorm[(tj << 9) + wj128 + (jt << 4) + lid];
#pragma unroll
        for (int mt = 0; mt < 4; ++mt)
#pragma unroll
            for (int r = 0; r < 4; ++r) {
                float bd = 3.4e38f; int bj = 0x7fffffff;
#pragma unroll
                for (int jt = 0; jt < 8; ++jt) {
                    int jg = (tj << 9) + wj128 + (jt << 4) + lid;
                    float d = yn[jt] - 2.f * acc[mt][jt][r];
                    if (d < bd || (d == bd && jg < bj)) { bd = d; bj = jg; }
                }
#pragma unroll
                for (int off = 1; off < 16; off <<= 1) {
                    float od = __shfl_xor(bd, off);
                    int   oj = __shfl_xor(bj, off);
                    if (od < bd || (od == bd && oj < bj)) { bd = od; bj = oj; }
                }
                if (lid == 0) {
                    float D = bwd[wid][kg][mt][r]; int J = bwj[wid][kg][mt][r];
                    if (bd < D || (bd == D && bj < J)) {
                        bwd[wid][kg][mt][r] = bd; bwj[wid][kg][mt][r] = bj;
                    }
                }
            }
    };

    // prologue: stage chunk 0, prefetch chunk 1
    LDA(0, aA0a, aA0b); LOADB(0);
    STA(aA0a, aA0b); STOREB(0);
    LDA(1, aA1a, aA1b); LOADB(1);
    __syncthreads();
    ZERO();

    for (int cp = 0; cp < 16; ++cp) {
        const int c0v = cp << 1, c1v = c0v + 1;
        // ---- even chunk (buf 0) ----
        STOREB(1);                                        // B(c0v+1)
        if (c0v < 30) { LDA(c0v + 2, aA0a, aA0b); LOADB(c0v + 2); }
        COMPUTE(0);
        __syncthreads();                                  // readers of sA/sB[0] done
        STA(aA1a, aA1b);                                  // A(c0v+1)
        __syncthreads();
        // ---- odd chunk (buf 1) ----
        if (c1v < 31) STOREB(0);                          // B(c1v+1)
        if (c1v < 30) { LDA(c1v + 2, aA1a, aA1b); LOADB(c1v + 2); }
        COMPUTE(1);
        if ((c1v & 15) == 15) { EPILOGUE(c1v >> 4); ZERO(); }
        __syncthreads();
        if (c1v < 31) { STA(aA0a, aA0b); __syncthreads(); }
    }

    // final merge across the 4 j-waves + writeout
    if (t < 128) {
        int wmv = t >> 6, local = t & 63;
        int mt = local >> 4, kg2 = (local >> 2) & 3, r = local & 3;
        float bd = bwd[(wmv << 2)][kg2][mt][r];
        int   bj = bwj[(wmv << 2)][kg2][mt][r];
#pragma unroll
        for (int wjv = 1; wjv < 4; ++wjv) {
            float od = bwd[(wmv << 2) + wjv][kg2][mt][r];
            int   oj = bwj[(wmv << 2) + wjv][kg2][mt][r];
            if (od < bd || (od == bd && oj < bj)) { bd = od; bj = oj; }
        }
        int m = mbase + m0 + (wmv << 6) + (mt << 4) + (kg2 << 2) + r;
        ws_idx[m] = bj;
        out_idx[m] = (float)bj;
    }
}

// ---------------- gather z_q (B,C,H,W) + per-block loss partials (NO atomics) ----------------
// 8192 blocks x 256 threads; each thread owns one (b, c4-group, hw) and loops the
// 4 c4 low bits -> one ws_idx load + one 64B codebook line per thread.
__global__ __launch_bounds__(256) void vq_gather(const float* __restrict__ cb,
    const float* __restrict__ z, const int* __restrict__ ws_idx,
    float* __restrict__ out, float* __restrict__ partials) {
    int base = blockIdx.x * 256 + threadIdx.x;   // 2^21 threads
    int hw  = base & 4095;
    int c4g = (base >> 12) & 31;
    int b   = base >> 17;
    int n   = (b << 12) | hw;
    int j   = ws_idx[n];
    float s = 0.f;
#pragma unroll
    for (int it = 0; it < 4; ++it) {
        int c4 = (c4g << 2) + it;
        float4 v = ((const float4*)cb)[(j << 7) + c4];
        long zo = ((long)((b << 9) + (c4 << 2))) * 4096 + hw;
        float z0 = z[zo], z1 = z[zo + 4096], z2 = z[zo + 8192], z3 = z[zo + 12288];
        out[zo] = v.x; out[zo + 4096] = v.y; out[zo + 8192] = v.z; out[zo + 12288] = v.w;
        float d0 = v.x - z0, d1 = v.y - z1, d2 = v.z - z2, d3 = v.w - z3;
        s += d0 * d0 + d1 * d1 + d2 * d2 + d3 * d3;
    }
#pragma unroll
    for (int off = 32; off > 0; off >>= 1) s += __shfl_xor(s, off);
    __shared__ float ps[4];
    if ((threadIdx.x & 63) == 0) ps[threadIdx.x >> 6] = s;
    __syncthreads();
    if (threadIdx.x == 0) partials[blockIdx.x] = ps[0] + ps[1] + ps[2] + ps[3];
}

// ---------------- final: reduce 8192 partials -> loss scalar ----------------
__global__ __launch_bounds__(1024) void vq_final(const float* __restrict__ partials,
                                                 float* __restrict__ out) {
    int t = threadIdx.x;
    float s = 0.f;
#pragma unroll
    for (int i = 0; i < NPART / 1024; ++i) s += partials[t + i * 1024];
#pragma unroll
    for (int off = 32; off > 0; off >>= 1) s += __shfl_xor(s, off);
    __shared__ float ps[16];
    if ((t & 63) == 0) ps[t >> 6] = s;
    __syncthreads();
    if (t == 0) {
        float tot = 0.f;
#pragma unroll
        for (int i = 0; i < 16; ++i) tot += ps[i];
        out[ZQ_ELEMS] = (1.f + BETA) * tot / 33554432.f;
    }
}

extern "C" void kernel_launch(void* const* d_in, const int* in_sizes, int n_in,
                              void* d_out, int out_size, void* d_ws, size_t ws_size,
                              hipStream_t stream) {
    const float* z  = (const float*)d_in[0];   // (16,512,64,64) fp32
    const float* cb = (const float*)d_in[1];   // (1024,512) fp32
    float* out = (float*)d_out;                // [z_q | loss | indices(float)]
    char* ws = (char*)d_ws;

    float* ynorm    = (float*)(ws + 1024);
    int*   ws_idx   = (int*)(ws + 8192);
    float* partials = (float*)(ws + 768 * 1024);          // 32 KB
    unsigned short* Bh = (unsigned short*)(ws + (1L << 20));
    unsigned short* Bl = (unsigned short*)(ws + (2L << 20));
    const size_t base = 3L << 20;
    unsigned short* Ah = (unsigned short*)(ws + base);

    // pick M-phasing from available workspace (deterministic in ws_size)
    int nphase = 1;
    while (nphase < 16) {
        size_t Asz = (size_t)(65536 / nphase) * 512 * 2;
        if (base + 2 * Asz <= ws_size) break;
        nphase <<= 1;
    }
    size_t Asz = (size_t)(65536 / nphase) * 512 * 2;
    unsigned short* Al = (unsigned short*)(ws + base + Asz);

    vq_prep<<<N_E, 64, 0, stream>>>(cb, Bh, Bl, ynorm);
    int PM = 65536 / nphase;
    for (int p = 0; p < nphase; ++p) {
        vq_pack<<<8192 / nphase, 256, 0, stream>>>(z, Ah, Al, p * (16 / nphase));
        vq_dist<<<PM / 128, 512, 0, stream>>>(Ah, Al, Bh, Bl, ynorm, ws_idx,
                                              out + ZQ_ELEMS + 1, p * PM);
    }
    vq_gather<<<NPART, 256, 0, stream>>>(cb, z, ws_idx, out, partials);
    vq_final<<<1, 1024, 0, stream>>>(partials, out);
}